// Round 4
// baseline (2015.042 us; speedup 1.0000x reference)
//
#include <hip/hip_runtime.h>
#include <math.h>

#define V 32000
#define T 512
#define NB 8
#define LN_EPS 1e-5f

typedef __attribute__((ext_vector_type(8))) short short8;
typedef __attribute__((ext_vector_type(4))) float f32x4;

__device__ __forceinline__ unsigned short f2b(float x) {
    unsigned int u = __float_as_uint(x);
    unsigned int r = (u + 0x7fffu + ((u >> 16) & 1u)) >> 16;
    return (unsigned short)r;
}
__device__ __forceinline__ float b2f(unsigned short h) {
    return __uint_as_float(((unsigned int)h) << 16);
}
// pack two floats to bf16 pair (round-half-up): low16=bf16(a), high16=bf16(b)
__device__ __forceinline__ unsigned int pack_rn(float a, float b) {
    unsigned int ua = __float_as_uint(a) + 0x8000u;
    unsigned int ub = __float_as_uint(b) + 0x8000u;
    return __builtin_amdgcn_perm(ub, ua, 0x07060302u);
}

// ---------------- K1: ml/mr modulation (pos MLP) ----------------
__global__ void k_mod(const float* __restrict__ pos, const float* __restrict__ W1,
                      const float* __restrict__ b1, const float* __restrict__ W2,
                      const float* __restrict__ b2, float* __restrict__ ml,
                      float* __restrict__ mr, unsigned short* __restrict__ mrb) {
    int t = blockIdx.x, tid = threadIdx.x;
    __shared__ float pos_s[64];
    __shared__ float hm_s[128];
    if (tid < 64) pos_s[tid] = pos[t * 64 + tid];
    __syncthreads();
    float acc = b1[tid];
#pragma unroll
    for (int p = 0; p < 64; p++) acc += pos_s[p] * W1[p * 128 + tid];
    float g = acc * 0.5f * (1.0f + erff(acc * 0.70710678118654752f)); // exact GELU
    hm_s[tid] = g;
    __syncthreads();
    float acc2 = b2[tid];
#pragma unroll
    for (int k = 0; k < 128; k++) acc2 += hm_s[k] * W2[k * 128 + tid];
    float val = 1.0f + 0.5f * tanhf(acc2);
    if (tid < 64) ml[t * 64 + tid] = val;
    else { int c = tid - 64; mr[t * 64 + c] = val; mrb[t * 64 + c] = f2b(val); }
}

// ---------------- K1b: gather core[:, x_t, :] -> contiguous bf16 pairs ----------------
// g[bt][k], k = i2*64 + j holds (core[2*i2][x][j], core[2*i2+1][x][j]) as bf16 pair.
// Vectorized (G13): f32x4 loads + uint4 store, 4x fewer memory instructions,
// identical coalescing (16 lanes x 16B = 256B row segments) and rounding.
__global__ void __launch_bounds__(256) k_gather(const int* __restrict__ ids,
                                                const float* __restrict__ core,
                                                unsigned int* __restrict__ g) {
    int bt = blockIdx.x;            // b*512 + t
    int b = bt >> 9, t = bt & 511;
    int x = ids[b * T + t];
    unsigned int* dst = g + (size_t)bt * 2048;
#pragma unroll
    for (int e = 0; e < 2; e++) {
        int k = (e * 256 + threadIdx.x) * 4;   // first of 4 consecutive uints
        int i2 = k >> 6, j = k & 63;           // j multiple of 4 -> same row for all 4
        f32x4 a = *reinterpret_cast<const f32x4*>(core + ((size_t)(2 * i2) * V + x) * 64 + j);
        f32x4 c = *reinterpret_cast<const f32x4*>(core + ((size_t)(2 * i2 + 1) * V + x) * 64 + j);
        uint4 o;
        o.x = pack_rn(a.x, c.x);
        o.y = pack_rn(a.y, c.y);
        o.z = pack_rn(a.z, c.z);
        o.w = pack_rn(a.w, c.w);
        *reinterpret_cast<uint4*>(dst + k) = o;
    }
}

// ---------------- K2: sequential recurrence, one block (1 wave) per batch elem ----------------
// Single wave per block: no __syncthreads needed. The only required ordering is
// ds_write(hm_s) -> ds_read(hm_s) visibility within the wave, provided by
// s_waitcnt lgkmcnt(0) (DS pipe is in-order per wave). Crucially this does NOT
// drain vmcnt, so the 2-step-ahead global prefetch (PF) stays in flight across
// steps; the compiler inserts fine-grained vmcnt(N) waits at the USE site.
__global__ void __launch_bounds__(64) k_scan(
    const unsigned int* __restrict__ g, const float* __restrict__ h0,
    const float* __restrict__ ml, const float* __restrict__ mr,
    const float* __restrict__ gam, const float* __restrict__ bet,
    unsigned short* __restrict__ hmod) {
    const int b = blockIdx.x, j = threadIdx.x;
    __shared__ float hm_s[64];
    float h = h0[j];
    const float gj = gam[j], bj = bet[j];
    const unsigned int* gb = g + (size_t)b * (512 * 2048);
    unsigned int B0[32], B1[32], B2[32], B3[32];
#pragma unroll
    for (int i = 0; i < 32; i++) B0[i] = gb[i * 64 + j];
#pragma unroll
    for (int i = 0; i < 32; i++) B1[i] = gb[2048 + i * 64 + j];

#define SCAN_BODY(TT, USE, PF)                                                \
    {                                                                         \
        int tp = (TT) + 2; if (tp > T - 1) tp = T - 1;                        \
        const unsigned int* gp = gb + (size_t)tp * 2048;                      \
        _Pragma("unroll")                                                     \
        for (int i = 0; i < 32; i++) PF[i] = gp[i * 64 + j];                  \
        float hmj = h * ml[(TT) * 64 + j];                                    \
        hmod[((TT) * 8 + b) * 64 + j] = f2b(hmj);                             \
        hm_s[j] = hmj;                                                        \
        asm volatile("s_waitcnt lgkmcnt(0)" ::: "memory");                    \
        float s0a = 0.f, s1a = 0.f, s0b = 0.f, s1b = 0.f;                     \
        _Pragma("unroll")                                                     \
        for (int i = 0; i < 16; i++) {                                        \
            unsigned int u = USE[i];                                          \
            s0a += __uint_as_float(u << 16) * hm_s[2 * i];                    \
            s1a += __uint_as_float(u & 0xffff0000u) * hm_s[2 * i + 1];        \
        }                                                                     \
        _Pragma("unroll")                                                     \
        for (int i = 16; i < 32; i++) {                                       \
            unsigned int u = USE[i];                                          \
            s0b += __uint_as_float(u << 16) * hm_s[2 * i];                    \
            s1b += __uint_as_float(u & 0xffff0000u) * hm_s[2 * i + 1];        \
        }                                                                     \
        float y = ((s0a + s0b) + (s1a + s1b)) * mr[(TT) * 64 + j];            \
        float sum = y, sq = y * y;                                            \
        _Pragma("unroll")                                                     \
        for (int m = 1; m < 64; m <<= 1) {                                    \
            sum += __shfl_xor(sum, m, 64);                                    \
            sq  += __shfl_xor(sq, m, 64);                                     \
        }                                                                     \
        float mu = sum * (1.f / 64.f);                                        \
        float var = sq * (1.f / 64.f) - mu * mu;                              \
        h = (y - mu) * rsqrtf(var + LN_EPS) * gj + bj;                        \
    }

    for (int t = 0; t < T; t += 4) {
        SCAN_BODY(t, B0, B2)
        SCAN_BODY(t + 1, B1, B3)
        SCAN_BODY(t + 2, B2, B0)
        SCAN_BODY(t + 3, B3, B1)
    }
#undef SCAN_BODY
}

// ---------------- K3: fused logits + LSE partials ----------------
// Block owns 8 v's (4000 blocks). Wave w keeps core[:, v0+w, :] as bf16 MFMA
// A-fragments in registers (loaded once). Per 32-t chunk:
//   preload: ALL stage-B hmod fragments (8 short8) + tgt -> in flight across
//            stage A and the barrier (issue-early / consume-late);
//   stage A: r[t,v,i] = sum_j core[i,v,j] mr[t,j]   (M=i, N=t) -> LDS b64-packed
//   stage B: batch 8 ds_read_b128 (all 4 t's), then 8 MFMA, then LSE tails.
// This removes the per-e serial chain {ds_read -> global load -> MFMA -> LSE}
// that left the wave idle ~90% of the time (VGPR_Count 52 showed the compiler
// kept nothing in flight).
#define BAR_LDS() do {                                             \
        asm volatile("s_waitcnt lgkmcnt(0)" ::: "memory");         \
        __builtin_amdgcn_s_barrier();                              \
    } while (0)

__global__ void __launch_bounds__(512, 4) k_logits(
    const float* __restrict__ core, const unsigned short* __restrict__ mrb,
    const unsigned short* __restrict__ hmod, const float* __restrict__ obias,
    const int* __restrict__ tgt, unsigned int* __restrict__ ws_ms,
    float* __restrict__ ws_tgt) {
    __shared__ __attribute__((aligned(16))) unsigned short r3s[8 * 2312];

    const int tid = threadIdx.x;
    const int w = tid >> 6;
    const int lane = tid & 63;
    const int q = lane >> 4;
    const int l15 = lane & 15;
    const int bx = blockIdx.x;
    const int v0 = bx * 8;
    const int myv = v0 + w;
    const int bb = l15 & 7;
    const int vp = (l15 & 7) * 2312;

    // persistent core A-fragments: cf[it*2+ks], A[m=i][k=j], i=it*16+l15, j=ks*32+q*8+e
    short8 cf[8];
#pragma unroll
    for (int it = 0; it < 4; it++) {
        const float* p = core + (((size_t)(it * 16 + l15)) * V + myv) * 64;
#pragma unroll
        for (int ks = 0; ks < 2; ks++) {
            f32x4 x0 = *reinterpret_cast<const f32x4*>(p + ks * 32 + q * 8);
            f32x4 x1 = *reinterpret_cast<const f32x4*>(p + ks * 32 + q * 8 + 4);
            union { short8 s; unsigned int u[4]; } pk;
            pk.u[0] = pack_rn(x0.x, x0.y);
            pk.u[1] = pack_rn(x0.z, x0.w);
            pk.u[2] = pack_rn(x1.x, x1.y);
            pk.u[3] = pack_rn(x1.z, x1.w);
            cf[it * 2 + ks] = pk.s;
        }
    }
    float biasv[4];
#pragma unroll
    for (int r = 0; r < 4; r++) biasv[r] = obias[v0 + (q & 1) * 4 + r];

    for (int ch = 0; ch < 16; ch++) {
        const int t0 = ch * 32;
        // ---- preload stage-B global operands (fly across stage A + barrier)
        short8 hb[8];
        int tg_e[4];
#pragma unroll
        for (int e = 0; e < 4; e++) {
            const int t = t0 + w * 4 + e;
            const unsigned short* hp = hmod + ((size_t)t * 8 + bb) * 64 + q * 8;
            hb[2 * e]     = *reinterpret_cast<const short8*>(hp);
            hb[2 * e + 1] = *reinterpret_cast<const short8*>(hp + 32);
            tg_e[e] = tgt[bb * T + t];
        }
        // ---- stage A: this wave's v, both 16-t tiles
#pragma unroll
        for (int tt = 0; tt < 2; tt++) {
            const int trow = t0 + tt * 16 + l15;
            short8 mf0 = *reinterpret_cast<const short8*>(mrb + trow * 64 + q * 8);
            short8 mf1 = *reinterpret_cast<const short8*>(mrb + trow * 64 + 32 + q * 8);
#pragma unroll
            for (int it = 0; it < 4; it++) {
                f32x4 acc = {0.f, 0.f, 0.f, 0.f};
                acc = __builtin_amdgcn_mfma_f32_16x16x32_bf16(cf[it * 2], mf0, acc, 0, 0, 0);
                acc = __builtin_amdgcn_mfma_f32_16x16x32_bf16(cf[it * 2 + 1], mf1, acc, 0, 0, 0);
                // C[m=i][n=t]: lane col=t-within-tile(l15), rows i=it*16+q*4+r
                uint2 dd;
                dd.x = pack_rn(acc.x, acc.y);
                dd.y = pack_rn(acc.z, acc.w);
                *reinterpret_cast<uint2*>(
                    &r3s[w * 2312 + (tt * 16 + l15) * 72 + it * 16 + q * 4]) = dd;
            }
        }
        BAR_LDS();
        // ---- stage B: batch all LDS reads, then all MFMA, then LSE tails
        short8 ra[8];
#pragma unroll
        for (int e = 0; e < 4; e++) {
            const int tl = w * 4 + e;
            ra[2 * e]     = *reinterpret_cast<const short8*>(&r3s[vp + tl * 72 + q * 8]);
            ra[2 * e + 1] = *reinterpret_cast<const short8*>(&r3s[vp + tl * 72 + 32 + q * 8]);
        }
#pragma unroll
        for (int e = 0; e < 4; e++) {
            const int t = t0 + w * 4 + e;
            f32x4 acc = {0.f, 0.f, 0.f, 0.f};
            acc = __builtin_amdgcn_mfma_f32_16x16x32_bf16(ra[2 * e], hb[2 * e], acc, 0, 0, 0);
            acc = __builtin_amdgcn_mfma_f32_16x16x32_bf16(ra[2 * e + 1], hb[2 * e + 1], acc, 0, 0, 0);
            float vals[4];
#pragma unroll
            for (int r = 0; r < 4; r++) vals[r] = acc[r] + biasv[r];
            // target logit
            if (q < 2 && l15 < 8) {
#pragma unroll
                for (int r = 0; r < 4; r++)
                    if (tg_e[e] == v0 + q * 4 + r) ws_tgt[l15 * T + t] = vals[r];
            }
            // LSE: 4 v's in-lane, then merge q^1 (covers all 8 v; q2/q3 are dups)
            float m4 = fmaxf(fmaxf(vals[0], vals[1]), fmaxf(vals[2], vals[3]));
            float s4 = __expf(vals[0] - m4) + __expf(vals[1] - m4) +
                       __expf(vals[2] - m4) + __expf(vals[3] - m4);
            float om = __shfl_xor(m4, 16, 64);
            float os = __shfl_xor(s4, 16, 64);
            float mm = fmaxf(m4, om);
            float mq = b2f(f2b(mm));  // quantize max BEFORE forming s (consistency)
            float ss = s4 * __expf(m4 - mq) + os * __expf(om - mq);
            if (q == 0 && l15 < 8) {
                ws_ms[(size_t)bx * 4096 + l15 * T + t] =
                    ((unsigned int)f2b(mq) << 16) | f2b(ss);
            }
        }
        BAR_LDS();
    }
}

// ---------------- reduces ----------------
__global__ void k_red1(const unsigned int* __restrict__ ws_ms,
                       float* __restrict__ o_m, float* __restrict__ o_s) {
    int bt = blockIdx.x * 256 + threadIdx.x;
    int kg = blockIdx.y;
    float m = -1e30f, s = 0.f;
    for (int kk = 0; kk < 100; kk++) {
        unsigned int pp = ws_ms[(size_t)(kg * 100 + kk) * 4096 + bt];
        float mk = b2f((unsigned short)(pp >> 16));
        float sk = b2f((unsigned short)(pp & 0xffff));
        float m2 = fmaxf(m, mk);
        s = s * __expf(m - m2) + sk * __expf(mk - m2);
        m = m2;
    }
    o_m[kg * 4096 + bt] = m; o_s[kg * 4096 + bt] = s;
}

__global__ void k_red2(const float* __restrict__ o_m, const float* __restrict__ o_s,
                       const float* __restrict__ wtgt, float* __restrict__ out) {
    int bt = blockIdx.x * 256 + threadIdx.x;
    float m = -1e30f, s = 0.f;
    for (int kg = 0; kg < 40; kg++) {
        float mk = o_m[kg * 4096 + bt], sk = o_s[kg * 4096 + bt];
        float m2 = fmaxf(m, mk);
        s = s * __expf(m - m2) + sk * __expf(mk - m2);
        m = m2;
    }
    float term = m + logf(s) - wtgt[bt];
    __shared__ float red[256];
    red[threadIdx.x] = term;
    __syncthreads();
    for (int st = 128; st > 0; st >>= 1) {
        if (threadIdx.x < st) red[threadIdx.x] += red[threadIdx.x + st];
        __syncthreads();
    }
    if (threadIdx.x == 0) atomicAdd(out, red[0] * (1.f / 4096.f));
}

extern "C" void kernel_launch(void* const* d_in, const int* in_sizes, int n_in,
                              void* d_out, int out_size, void* d_ws, size_t ws_size,
                              hipStream_t stream) {
    const int*   ids   = (const int*)d_in[0];
    const int*   tgt   = (const int*)d_in[1];
    const float* core  = (const float*)d_in[2];
    const float* h0    = (const float*)d_in[3];
    const float* pos   = (const float*)d_in[4];
    const float* W1    = (const float*)d_in[5];
    const float* b1    = (const float*)d_in[6];
    const float* W2    = (const float*)d_in[7];
    const float* b2    = (const float*)d_in[8];
    const float* obias = (const float*)d_in[9];
    const float* gam   = (const float*)d_in[10];
    const float* bet   = (const float*)d_in[11];

    char* ws = (char*)d_ws;
    float*          ws_ml  = (float*)(ws + 0);              // 512*64*4   = 131072
    float*          ws_mr  = (float*)(ws + 131072);         // 131072
    unsigned short* ws_mrb = (unsigned short*)(ws + 262144);// 512*64*2   = 65536
    unsigned short* ws_hm  = (unsigned short*)(ws + 327680);// 512*8*64*2 = 524288
    float*          ws_tg  = (float*)(ws + 851968);         // 4096*4     = 16384
    // g (33.5 MB) aliases the front of ws_ms (65.5 MB): g is dead (scan done)
    // before k_logits writes ws_ms.
    unsigned int*   g      = (unsigned int*)(ws + 868352);
    unsigned int*   ws_ms  = (unsigned int*)(ws + 868352);  // 4000*4096*4 = 65536000
    float*          o2m    = (float*)(ws + 66404352);       // 40*4096*4  = 655360
    float*          o2s    = (float*)(ws + 67059712);       // 655360  (end 67715072)

    hipMemsetAsync(d_out, 0, sizeof(float), stream);

    k_mod<<<512, 128, 0, stream>>>(pos, W1, b1, W2, b2, ws_ml, ws_mr, ws_mrb);
    k_gather<<<4096, 256, 0, stream>>>(ids, core, g);
    k_scan<<<NB, 64, 0, stream>>>(g, h0, ws_ml, ws_mr, gam, bet, ws_hm);
    k_logits<<<4000, 512, 0, stream>>>(core, ws_mrb, ws_hm, obias, tgt, ws_ms, ws_tg);
    k_red1<<<dim3(16, 40), 256, 0, stream>>>(ws_ms, o2m, o2s);
    k_red2<<<16, 256, 0, stream>>>(o2m, o2s, ws_tg, (float*)d_out);
}

// Round 8
// 1687.444 us; speedup vs baseline: 1.1941x; 1.1941x over previous
//
#include <hip/hip_runtime.h>
#include <math.h>

#define V 32000
#define T 512
#define NB 8
#define LN_EPS 1e-5f

typedef __attribute__((ext_vector_type(8))) short short8;
typedef __attribute__((ext_vector_type(4))) float f32x4;

__device__ __forceinline__ unsigned short f2b(float x) {
    unsigned int u = __float_as_uint(x);
    unsigned int r = (u + 0x7fffu + ((u >> 16) & 1u)) >> 16;
    return (unsigned short)r;
}
__device__ __forceinline__ float b2f(unsigned short h) {
    return __uint_as_float(((unsigned int)h) << 16);
}
// pack two floats to bf16 pair (round-half-up): low16=bf16(a), high16=bf16(b)
__device__ __forceinline__ unsigned int pack_rn(float a, float b) {
    unsigned int ua = __float_as_uint(a) + 0x8000u;
    unsigned int ub = __float_as_uint(b) + 0x8000u;
    return __builtin_amdgcn_perm(ub, ua, 0x07060302u);
}

// ---------------- K1: ml/mr modulation (pos MLP) ----------------
__global__ void k_mod(const float* __restrict__ pos, const float* __restrict__ W1,
                      const float* __restrict__ b1, const float* __restrict__ W2,
                      const float* __restrict__ b2, float* __restrict__ ml,
                      float* __restrict__ mr, unsigned short* __restrict__ mrb) {
    int t = blockIdx.x, tid = threadIdx.x;
    __shared__ float pos_s[64];
    __shared__ float hm_s[128];
    if (tid < 64) pos_s[tid] = pos[t * 64 + tid];
    __syncthreads();
    float acc = b1[tid];
#pragma unroll
    for (int p = 0; p < 64; p++) acc += pos_s[p] * W1[p * 128 + tid];
    float g = acc * 0.5f * (1.0f + erff(acc * 0.70710678118654752f)); // exact GELU
    hm_s[tid] = g;
    __syncthreads();
    float acc2 = b2[tid];
#pragma unroll
    for (int k = 0; k < 128; k++) acc2 += hm_s[k] * W2[k * 128 + tid];
    float val = 1.0f + 0.5f * tanhf(acc2);
    if (tid < 64) ml[t * 64 + tid] = val;
    else { int c = tid - 64; mr[t * 64 + c] = val; mrb[t * 64 + c] = f2b(val); }
}

// ---------------- K1b: gather core[:, x_t, :] -> contiguous bf16 pairs ----------------
__global__ void __launch_bounds__(256) k_gather(const int* __restrict__ ids,
                                                const float* __restrict__ core,
                                                unsigned int* __restrict__ g) {
    int bt = blockIdx.x;            // b*512 + t
    int b = bt >> 9, t = bt & 511;
    int x = ids[b * T + t];
    unsigned int* dst = g + (size_t)bt * 2048;
#pragma unroll
    for (int e = 0; e < 2; e++) {
        int k = (e * 256 + threadIdx.x) * 4;   // first of 4 consecutive uints
        int i2 = k >> 6, j = k & 63;           // j multiple of 4 -> same row for all 4
        f32x4 a = *reinterpret_cast<const f32x4*>(core + ((size_t)(2 * i2) * V + x) * 64 + j);
        f32x4 c = *reinterpret_cast<const f32x4*>(core + ((size_t)(2 * i2 + 1) * V + x) * 64 + j);
        uint4 o;
        o.x = pack_rn(a.x, c.x);
        o.y = pack_rn(a.y, c.y);
        o.z = pack_rn(a.z, c.z);
        o.w = pack_rn(a.w, c.w);
        *reinterpret_cast<uint4*>(dst + k) = o;
    }
}

// ---------------- K2: sequential recurrence, one block (1 wave) per batch elem ----------------
__global__ void __launch_bounds__(64) k_scan(
    const unsigned int* __restrict__ g, const float* __restrict__ h0,
    const float* __restrict__ ml, const float* __restrict__ mr,
    const float* __restrict__ gam, const float* __restrict__ bet,
    unsigned short* __restrict__ hmod) {
    const int b = blockIdx.x, j = threadIdx.x;
    __shared__ float hm_s[64];
    float h = h0[j];
    const float gj = gam[j], bj = bet[j];
    const unsigned int* gb = g + (size_t)b * (512 * 2048);
    unsigned int B0[32], B1[32], B2[32], B3[32];
#pragma unroll
    for (int i = 0; i < 32; i++) B0[i] = gb[i * 64 + j];
#pragma unroll
    for (int i = 0; i < 32; i++) B1[i] = gb[2048 + i * 64 + j];

#define SCAN_BODY(TT, USE, PF)                                                \
    {                                                                         \
        int tp = (TT) + 2; if (tp > T - 1) tp = T - 1;                        \
        const unsigned int* gp = gb + (size_t)tp * 2048;                      \
        _Pragma("unroll")                                                     \
        for (int i = 0; i < 32; i++) PF[i] = gp[i * 64 + j];                  \
        float hmj = h * ml[(TT) * 64 + j];                                    \
        hmod[((TT) * 8 + b) * 64 + j] = f2b(hmj);                             \
        hm_s[j] = hmj;                                                        \
        asm volatile("s_waitcnt lgkmcnt(0)" ::: "memory");                    \
        float s0a = 0.f, s1a = 0.f, s0b = 0.f, s1b = 0.f;                     \
        _Pragma("unroll")                                                     \
        for (int i = 0; i < 16; i++) {                                        \
            unsigned int u = USE[i];                                          \
            s0a += __uint_as_float(u << 16) * hm_s[2 * i];                    \
            s1a += __uint_as_float(u & 0xffff0000u) * hm_s[2 * i + 1];        \
        }                                                                     \
        _Pragma("unroll")                                                     \
        for (int i = 16; i < 32; i++) {                                       \
            unsigned int u = USE[i];                                          \
            s0b += __uint_as_float(u << 16) * hm_s[2 * i];                    \
            s1b += __uint_as_float(u & 0xffff0000u) * hm_s[2 * i + 1];        \
        }                                                                     \
        float y = ((s0a + s0b) + (s1a + s1b)) * mr[(TT) * 64 + j];            \
        float sum = y, sq = y * y;                                            \
        _Pragma("unroll")                                                     \
        for (int m = 1; m < 64; m <<= 1) {                                    \
            sum += __shfl_xor(sum, m, 64);                                    \
            sq  += __shfl_xor(sq, m, 64);                                     \
        }                                                                     \
        float mu = sum * (1.f / 64.f);                                        \
        float var = sq * (1.f / 64.f) - mu * mu;                              \
        h = (y - mu) * rsqrtf(var + LN_EPS) * gj + bj;                        \
    }

    for (int t = 0; t < T; t += 4) {
        SCAN_BODY(t, B0, B2)
        SCAN_BODY(t + 1, B1, B3)
        SCAN_BODY(t + 2, B2, B0)
        SCAN_BODY(t + 3, B3, B1)
    }
#undef SCAN_BODY
}

// ---------------- K3: fused logits + LSE partials ----------------
// Block owns 8 v's (4000 blocks). Wave w keeps core[:, v0+w, :] as bf16 MFMA
// A-fragments in registers. Structure:
//  * double-buffered r3s + software pipeline: one barrier region holds
//    STAGE_A(ch+1) (writes buf X) || STAGE_B(ch) (reads buf Y) -- independent
//    work co-scheduled so each stage's latency hides under the other.
//    17 barriers instead of 32.
//  * stage B packs TWO t's per MFMA block-diagonally: A rows 0..7=(v,t_even),
//    8..15=(v,t_odd); B cols likewise. Valid C quadrants are diagonal; lane
//    validity (q>>1)==(l15>>3). Stage-B MFMA 8->4, LSE tails 4->2 per
//    wave-chunk, no duplicate-lane work.
#define BAR_LDS() do {                                             \
        asm volatile("s_waitcnt lgkmcnt(0)" ::: "memory");         \
        __builtin_amdgcn_s_barrier();                              \
    } while (0)

__global__ void __launch_bounds__(512, 4) k_logits(
    const float* __restrict__ core, const unsigned short* __restrict__ mrb,
    const unsigned short* __restrict__ hmod, const float* __restrict__ obias,
    const int* __restrict__ tgt, unsigned int* __restrict__ ws_ms,
    float* __restrict__ ws_tgt) {
    __shared__ __attribute__((aligned(16))) unsigned short r3s[2][8 * 2312];

    const int tid = threadIdx.x;
    const int w = tid >> 6;
    const int lane = tid & 63;
    const int q = lane >> 4;
    const int l15 = lane & 15;
    const int bx = blockIdx.x;
    const int v0 = bx * 8;
    const int myv = v0 + w;
    const int half = l15 >> 3;          // 0: t-even lanes, 1: t-odd lanes
    const int bb = l15 & 7;             // batch index
    const int vp = bb * 2312;           // r3s region of wave owning v=v0+bb
    const bool vrow_ok = ((q >> 1) == half);  // lane's C rows are a valid quadrant
    const bool writer = (q == 2 * half);      // q==0 (half0) / q==2 (half1)

    // persistent core A-fragments: cf[it*2+ks], A[m=i][k=j], i=it*16+l15, j=ks*32+q*8+e
    short8 cf[8];
#pragma unroll
    for (int it = 0; it < 4; it++) {
        const float* p = core + (((size_t)(it * 16 + l15)) * V + myv) * 64;
#pragma unroll
        for (int ks = 0; ks < 2; ks++) {
            f32x4 x0 = *reinterpret_cast<const f32x4*>(p + ks * 32 + q * 8);
            f32x4 x1 = *reinterpret_cast<const f32x4*>(p + ks * 32 + q * 8 + 4);
            union { short8 s; unsigned int u[4]; } pk;
            pk.u[0] = pack_rn(x0.x, x0.y);
            pk.u[1] = pack_rn(x0.z, x0.w);
            pk.u[2] = pack_rn(x1.x, x1.y);
            pk.u[3] = pack_rn(x1.z, x1.w);
            cf[it * 2 + ks] = pk.s;
        }
    }
    float biasv[4];
#pragma unroll
    for (int r = 0; r < 4; r++) biasv[r] = obias[v0 + (q & 1) * 4 + r];

// STAGE_A: compute r[t, myv, i] for 32 t's starting at T0v into r3s[BUF]
#define STAGE_A(T0v, BUF)                                                     \
    {                                                                         \
        const int t0a_ = (T0v);                                               \
        _Pragma("unroll")                                                     \
        for (int tt = 0; tt < 2; tt++) {                                      \
            const int trow = t0a_ + tt * 16 + l15;                            \
            short8 mf0 = *reinterpret_cast<const short8*>(mrb + trow * 64 + q * 8); \
            short8 mf1 = *reinterpret_cast<const short8*>(mrb + trow * 64 + 32 + q * 8); \
            _Pragma("unroll")                                                 \
            for (int it = 0; it < 4; it++) {                                  \
                f32x4 acc = {0.f, 0.f, 0.f, 0.f};                             \
                acc = __builtin_amdgcn_mfma_f32_16x16x32_bf16(cf[it * 2], mf0, acc, 0, 0, 0); \
                acc = __builtin_amdgcn_mfma_f32_16x16x32_bf16(cf[it * 2 + 1], mf1, acc, 0, 0, 0); \
                uint2 dd;                                                     \
                dd.x = pack_rn(acc.x, acc.y);                                 \
                dd.y = pack_rn(acc.z, acc.w);                                 \
                *reinterpret_cast<uint2*>(                                    \
                    &r3s[BUF][w * 2312 + (tt * 16 + l15) * 72 + it * 16 + q * 4]) = dd; \
            }                                                                 \
        }                                                                     \
    }

// STAGE_B: logits + LSE for 4 t's (2 MFMA pairs, 2 t's each block-diagonal)
#define STAGE_B(T0v, BUF)                                                     \
    {                                                                         \
        const int t0b_ = (T0v);                                               \
        _Pragma("unroll")                                                     \
        for (int p_ = 0; p_ < 2; p_++) {                                      \
            const int tl_ = w * 4 + 2 * p_ + half;                            \
            const int tb_ = t0b_ + tl_;                                       \
            const unsigned short* hp_ = hmod + ((size_t)tb_ * 8 + bb) * 64 + q * 8; \
            short8 hb0_ = *reinterpret_cast<const short8*>(hp_);              \
            short8 hb1_ = *reinterpret_cast<const short8*>(hp_ + 32);         \
            short8 ra0_ = *reinterpret_cast<const short8*>(&r3s[BUF][vp + tl_ * 72 + q * 8]); \
            short8 ra1_ = *reinterpret_cast<const short8*>(&r3s[BUF][vp + tl_ * 72 + 32 + q * 8]); \
            f32x4 acc_ = {0.f, 0.f, 0.f, 0.f};                                \
            acc_ = __builtin_amdgcn_mfma_f32_16x16x32_bf16(ra0_, hb0_, acc_, 0, 0, 0); \
            acc_ = __builtin_amdgcn_mfma_f32_16x16x32_bf16(ra1_, hb1_, acc_, 0, 0, 0); \
            float vals_[4];                                                   \
            _Pragma("unroll")                                                 \
            for (int r = 0; r < 4; r++) vals_[r] = acc_[r] + biasv[r];        \
            if (vrow_ok) {                                                    \
                int tg_ = tgt[bb * T + tb_];                                  \
                _Pragma("unroll")                                             \
                for (int r = 0; r < 4; r++)                                   \
                    if (tg_ == v0 + (q & 1) * 4 + r) ws_tgt[bb * T + tb_] = vals_[r]; \
            }                                                                 \
            float m4_ = fmaxf(fmaxf(vals_[0], vals_[1]), fmaxf(vals_[2], vals_[3])); \
            float s4_ = __expf(vals_[0] - m4_) + __expf(vals_[1] - m4_) +     \
                        __expf(vals_[2] - m4_) + __expf(vals_[3] - m4_);      \
            float om_ = __shfl_xor(m4_, 16, 64);                              \
            float os_ = __shfl_xor(s4_, 16, 64);                              \
            float mm_ = fmaxf(m4_, om_);                                      \
            float mq_ = b2f(f2b(mm_));                                        \
            float ss_ = s4_ * __expf(m4_ - mq_) + os_ * __expf(om_ - mq_);    \
            if (writer) {                                                     \
                ws_ms[(size_t)bx * 4096 + bb * T + tb_] =                     \
                    ((unsigned int)f2b(mq_) << 16) | f2b(ss_);                \
            }                                                                 \
        }                                                                     \
    }

    STAGE_A(0, 0);
    BAR_LDS();
#pragma unroll 1
    for (int ch = 0; ch < 16; ch += 2) {
        STAGE_A((ch + 1) * 32, 1);   // prefetch-compute next chunk into buf1
        STAGE_B(ch * 32, 0);         // consume current chunk from buf0
        BAR_LDS();
        if (ch + 2 < 16) STAGE_A((ch + 2) * 32, 0);
        STAGE_B((ch + 1) * 32, 1);
        BAR_LDS();
    }
#undef STAGE_A
#undef STAGE_B
}

// ---------------- reduces ----------------
__global__ void k_red1(const unsigned int* __restrict__ ws_ms,
                       float* __restrict__ o_m, float* __restrict__ o_s) {
    int bt = blockIdx.x * 256 + threadIdx.x;
    int kg = blockIdx.y;
    float m = -1e30f, s = 0.f;
    for (int kk = 0; kk < 100; kk++) {
        unsigned int pp = ws_ms[(size_t)(kg * 100 + kk) * 4096 + bt];
        float mk = b2f((unsigned short)(pp >> 16));
        float sk = b2f((unsigned short)(pp & 0xffff));
        float m2 = fmaxf(m, mk);
        s = s * __expf(m - m2) + sk * __expf(mk - m2);
        m = m2;
    }
    o_m[kg * 4096 + bt] = m; o_s[kg * 4096 + bt] = s;
}

__global__ void k_red2(const float* __restrict__ o_m, const float* __restrict__ o_s,
                       const float* __restrict__ wtgt, float* __restrict__ out) {
    int bt = blockIdx.x * 256 + threadIdx.x;
    float m = -1e30f, s = 0.f;
    for (int kg = 0; kg < 40; kg++) {
        float mk = o_m[kg * 4096 + bt], sk = o_s[kg * 4096 + bt];
        float m2 = fmaxf(m, mk);
        s = s * __expf(m - m2) + sk * __expf(mk - m2);
        m = m2;
    }
    float term = m + logf(s) - wtgt[bt];
    __shared__ float red[256];
    red[threadIdx.x] = term;
    __syncthreads();
    for (int st = 128; st > 0; st >>= 1) {
        if (threadIdx.x < st) red[threadIdx.x] += red[threadIdx.x + st];
        __syncthreads();
    }
    if (threadIdx.x == 0) atomicAdd(out, red[0] * (1.f / 4096.f));
}

extern "C" void kernel_launch(void* const* d_in, const int* in_sizes, int n_in,
                              void* d_out, int out_size, void* d_ws, size_t ws_size,
                              hipStream_t stream) {
    const int*   ids   = (const int*)d_in[0];
    const int*   tgt   = (const int*)d_in[1];
    const float* core  = (const float*)d_in[2];
    const float* h0    = (const float*)d_in[3];
    const float* pos   = (const float*)d_in[4];
    const float* W1    = (const float*)d_in[5];
    const float* b1    = (const float*)d_in[6];
    const float* W2    = (const float*)d_in[7];
    const float* b2    = (const float*)d_in[8];
    const float* obias = (const float*)d_in[9];
    const float* gam   = (const float*)d_in[10];
    const float* bet   = (const float*)d_in[11];

    char* ws = (char*)d_ws;
    float*          ws_ml  = (float*)(ws + 0);              // 512*64*4   = 131072
    float*          ws_mr  = (float*)(ws + 131072);         // 131072
    unsigned short* ws_mrb = (unsigned short*)(ws + 262144);// 512*64*2   = 65536
    unsigned short* ws_hm  = (unsigned short*)(ws + 327680);// 512*8*64*2 = 524288
    float*          ws_tg  = (float*)(ws + 851968);         // 4096*4     = 16384
    // g (33.5 MB) aliases the front of ws_ms (65.5 MB): g is dead (scan done)
    // before k_logits writes ws_ms.
    unsigned int*   g      = (unsigned int*)(ws + 868352);
    unsigned int*   ws_ms  = (unsigned int*)(ws + 868352);  // 4000*4096*4 = 65536000
    float*          o2m    = (float*)(ws + 66404352);       // 40*4096*4  = 655360
    float*          o2s    = (float*)(ws + 67059712);       // 655360  (end 67715072)

    hipMemsetAsync(d_out, 0, sizeof(float), stream);

    k_mod<<<512, 128, 0, stream>>>(pos, W1, b1, W2, b2, ws_ml, ws_mr, ws_mrb);
    k_gather<<<4096, 256, 0, stream>>>(ids, core, g);
    k_scan<<<NB, 64, 0, stream>>>(g, h0, ws_ml, ws_mr, gam, bet, ws_hm);
    k_logits<<<4000, 512, 0, stream>>>(core, ws_mrb, ws_hm, obias, tgt, ws_ms, ws_tg);
    k_red1<<<dim3(16, 40), 256, 0, stream>>>(ws_ms, o2m, o2s);
    k_red2<<<16, 256, 0, stream>>>(o2m, o2s, ws_tg, (float*)d_out);
}